// Round 2
// baseline (182.877 us; speedup 1.0000x reference)
//
#include <hip/hip_runtime.h>
#include <stdint.h>

#define Bn   8
#define CIN  64
#define Hh   128
#define Wh   128
#define COUT 64
#define Tt   9
#define HO   128
#define WO   128

typedef __attribute__((ext_vector_type(8))) short short8;   // 8 bf16 = 4 VGPRs
typedef __attribute__((ext_vector_type(4))) float floatx4;  // MFMA acc

// Module-scope device scratch: avoids d_ws entirely (R1 failed because
// xT+wbf exceeded ws_size and prep_w overwrote the harness's pristine
// input copies -> replays diverged). 16 MiB + 72 KiB, load-time alloc.
__device__ uint16_t g_xT[(size_t)Bn * Hh * Wh * CIN];   // bf16 NHWC x
__device__ uint16_t g_wbf[Tt * COUT * CIN];             // bf16 A-fragment order

__device__ __forceinline__ uint16_t bf16_rne(float f) {
    uint32_t u = __builtin_bit_cast(uint32_t, f);
    uint32_t r = u + 0x7fffu + ((u >> 16) & 1u);
    return (uint16_t)(r >> 16);
}
__device__ __forceinline__ float bflo(uint32_t u) { return __builtin_bit_cast(float, u << 16); }
__device__ __forceinline__ float bfhi(uint32_t u) { return __builtin_bit_cast(float, u & 0xffff0000u); }
__device__ __forceinline__ uint32_t rne1(float f) {
    uint32_t u = __builtin_bit_cast(uint32_t, f);
    return (u + 0x7fffu + ((u >> 16) & 1u)) >> 16;
}

// ---------------------------------------------------------------------------
// Kernel 1: x NCHW fp32 -> g_xT NHWC bf16.  Block per (b, y): 1024 blocks.
// ---------------------------------------------------------------------------
__global__ __launch_bounds__(256) void transpose_x(const float* __restrict__ x) {
    int b = blockIdx.x >> 7;
    int y = blockIdx.x & 127;
    __shared__ uint16_t tile[64][130];   // +2 pad: conflict-free column reads

    const float* src = x + ((size_t)b * CIN) * (Hh * Wh) + (size_t)y * Wh;
    int t    = threadIdx.x;
    int xi   = t & 127;
    int csub = t >> 7;     // 0..1
    #pragma unroll
    for (int cc = 0; cc < 64; cc += 2) {
        int c = cc + csub;
        tile[c][xi] = bf16_rne(src[(size_t)c * (Hh * Wh) + xi]);
    }
    __syncthreads();

    uint32_t* dst = (uint32_t*)(g_xT + (((size_t)b * Hh + y) * Wh) * CIN);
    int d  = t & 31;    // dword within 128B channel row
    int xo = t >> 5;    // 0..7
    #pragma unroll
    for (int xx = 0; xx < 128; xx += 8) {
        int xg = xx + xo;
        uint32_t lo = tile[2 * d][xg];
        uint32_t hi = tile[2 * d + 1][xg];
        dst[xg * 32 + d] = lo | (hi << 16);
    }
}

// ---------------------------------------------------------------------------
// Kernel 2: weight (COUT,CIN,3,3) fp32 -> bf16 in MFMA A-fragment order:
// g_wbf[t][ks][mt][q][o15][j]  (elements), so a-frag load = base + lane*8.
// ---------------------------------------------------------------------------
__global__ __launch_bounds__(256) void prep_w(const float* __restrict__ w) {
    int tid = blockIdx.x * 256 + threadIdx.x;   // 36864 total
    int t   = tid >> 12;
    int rem = tid & 4095;
    int o   = rem >> 6;
    int c   = rem & 63;
    float v = w[(size_t)(o * 64 + c) * 9 + t];
    int ks = c >> 5, q = (c >> 3) & 3, j = c & 7;
    int mt = o >> 4, o15 = o & 15;
    g_wbf[t * 4096 + ks * 2048 + mt * 512 + q * 128 + o15 * 8 + j] = bf16_rne(v);
}

// ---------------------------------------------------------------------------
// Kernel 3: main DCN. Block = 256 thr (4 waves), each wave: 16 pixels x all
// 64 COUT. Lane owns pixel (lane&15) and channels (lane>>4)*8+j per k-step.
// No LDS, no barriers. 2048 blocks.
// ---------------------------------------------------------------------------
__global__ __launch_bounds__(256) void dcn_main(
        const float* __restrict__ offset, const float* __restrict__ mask,
        const float* __restrict__ bias, float* __restrict__ out) {
    int blk   = blockIdx.x;
    int b     = blk >> 8;
    int strip = blk & 255;
    int lane  = threadIdx.x & 63;
    int wave  = threadIdx.x >> 6;
    int n15   = lane & 15;
    int q     = lane >> 4;
    int p     = strip * 64 + wave * 16 + n15;   // pixel in [0,16384)
    int i     = p >> 7, j = p & 127;

    floatx4 acc[4] = {{0.f,0.f,0.f,0.f},{0.f,0.f,0.f,0.f},
                      {0.f,0.f,0.f,0.f},{0.f,0.f,0.f,0.f}};

    const float*    offB = offset + (size_t)b * (2 * Tt * HO * WO);
    const float*    mskB = mask   + (size_t)b * (Tt * HO * WO);
    const uint16_t* xb   = g_xT   + (size_t)b * (Hh * Wh * CIN);

    #pragma unroll
    for (int t = 0; t < Tt; ++t) {
        const int ky = t / 3, kx = t % 3;
        float dy = offB[(2 * t)     * (HO * WO) + p];
        float dx = offB[(2 * t + 1) * (HO * WO) + p];
        float m  = mskB[t * (HO * WO) + p];

        float py = dy + (float)(i + ky - 1);
        float px = dx + (float)(j + kx - 1);
        float fy = floorf(py), fx = floorf(px);
        int   y0 = (int)fy,    x0 = (int)fx;
        float ly = py - fy,    lx = px - fx;
        float hy = 1.f - ly,   hx = 1.f - lx;

        bool vy0 = (y0 >= 0) && (y0 < Hh);
        bool vy1 = (y0 >= -1) && (y0 < Hh - 1);
        bool vx0 = (x0 >= 0) && (x0 < Wh);
        bool vx1 = (x0 >= -1) && (x0 < Wh - 1);

        float w00 = (vy0 && vx0) ? hy * hx * m : 0.f;
        float w01 = (vy0 && vx1) ? hy * lx * m : 0.f;
        float w10 = (vy1 && vx0) ? ly * hx * m : 0.f;
        float w11 = (vy1 && vx1) ? ly * lx * m : 0.f;

        int y0c = min(max(y0, 0), Hh - 1), y1c = min(max(y0 + 1, 0), Hh - 1);
        int x0c = min(max(x0, 0), Wh - 1), x1c = min(max(x0 + 1, 0), Wh - 1);

        const uint16_t* r0  = xb + (size_t)(y0c * Wh) * CIN;
        const uint16_t* r1  = xb + (size_t)(y1c * Wh) * CIN;
        const uint16_t* p00 = r0 + x0c * CIN;
        const uint16_t* p01 = r0 + x1c * CIN;
        const uint16_t* p10 = r1 + x0c * CIN;
        const uint16_t* p11 = r1 + x1c * CIN;

        union U4 { uint4 v; uint32_t u[4]; };
        short8 bfrag[2];
        #pragma unroll
        for (int ks = 0; ks < 2; ++ks) {
            int c = q * 8 + ks * 32;
            U4 u00, u01, u10, u11;
            u00.v = *(const uint4*)(p00 + c);
            u01.v = *(const uint4*)(p01 + c);
            u10.v = *(const uint4*)(p10 + c);
            u11.v = *(const uint4*)(p11 + c);
            union { uint32_t u[4]; short8 s; } pk;
            #pragma unroll
            for (int e = 0; e < 4; ++e) {
                float lo = w00 * bflo(u00.u[e]) + w01 * bflo(u01.u[e])
                         + w10 * bflo(u10.u[e]) + w11 * bflo(u11.u[e]);
                float hi = w00 * bfhi(u00.u[e]) + w01 * bfhi(u01.u[e])
                         + w10 * bfhi(u10.u[e]) + w11 * bfhi(u11.u[e]);
                pk.u[e] = rne1(lo) | (rne1(hi) << 16);
            }
            bfrag[ks] = pk.s;
        }

        const uint16_t* wt = g_wbf + t * 4096;
        #pragma unroll
        for (int ks = 0; ks < 2; ++ks) {
            #pragma unroll
            for (int mt = 0; mt < 4; ++mt) {
                short8 a = *(const short8*)(wt + ks * 2048 + mt * 512 + lane * 8);
                acc[mt] = __builtin_amdgcn_mfma_f32_16x16x32_bf16(a, bfrag[ks], acc[mt], 0, 0, 0);
            }
        }
    }

    // Epilogue: D row = q*4+reg (output channel within 16-block), col = pixel.
    #pragma unroll
    for (int mt = 0; mt < 4; ++mt) {
        #pragma unroll
        for (int r = 0; r < 4; ++r) {
            int o = mt * 16 + q * 4 + r;
            out[(size_t)(b * COUT + o) * (HO * WO) + p] = acc[mt][r] + bias[o];
        }
    }
}

extern "C" void kernel_launch(void* const* d_in, const int* in_sizes, int n_in,
                              void* d_out, int out_size, void* d_ws, size_t ws_size,
                              hipStream_t stream) {
    const float* x      = (const float*)d_in[0];
    const float* offset = (const float*)d_in[1];
    const float* mask   = (const float*)d_in[2];
    const float* weight = (const float*)d_in[3];
    const float* bias   = (const float*)d_in[4];
    (void)d_ws; (void)ws_size;

    transpose_x<<<Bn * Hh, 256, 0, stream>>>(x);
    prep_w<<<(Tt * COUT * CIN) / 256, 256, 0, stream>>>(weight);
    dcn_main<<<Bn * 256, 256, 0, stream>>>(offset, mask, bias, (float*)d_out);
}

// Round 3
// 178.924 us; speedup vs baseline: 1.0221x; 1.0221x over previous
//
#include <hip/hip_runtime.h>
#include <stdint.h>

#define Bn   8
#define CIN  64
#define Hh   128
#define Wh   128
#define COUT 64
#define Tt   9
#define HO   128
#define WO   128
#define HW   (HO * WO)

typedef _Float16 h16;
typedef __attribute__((ext_vector_type(2))) _Float16 h2;
typedef __attribute__((ext_vector_type(8))) _Float16 h8;
typedef __attribute__((ext_vector_type(4))) float   f4;

// Module-scope scratch (NOT d_ws: R1 overflowed ws_size and corrupted the
// harness's pristine inputs). 16 MiB fp16 NHWC x + 72 KiB fp16 weights.
__device__ h16 g_xT[(size_t)Bn * Hh * Wh * CIN];
__device__ h16 g_wh[Tt * COUT * CIN];

// ---------------------------------------------------------------------------
// prep: blocks [0,1024) transpose x NCHW fp32 -> g_xT NHWC fp16 (block per
// (b,y)); blocks [1024,1168) repack weight -> fp16 MFMA A-fragment order.
// ---------------------------------------------------------------------------
__global__ __launch_bounds__(256) void prep(const float* __restrict__ x,
                                            const float* __restrict__ w) {
    if (blockIdx.x >= Bn * Hh) {
        int tid = (blockIdx.x - Bn * Hh) * 256 + threadIdx.x;   // 36864
        int t   = tid >> 12;
        int rem = tid & 4095;
        int o   = rem >> 6;
        int c   = rem & 63;
        float v = w[(size_t)(o * 64 + c) * 9 + t];
        int ks = c >> 5, q = (c >> 3) & 3, j = c & 7;
        int mt = o >> 4, o15 = o & 15;
        g_wh[t * 4096 + ks * 2048 + mt * 512 + q * 128 + o15 * 8 + j] = (h16)v;
        return;
    }
    int b = blockIdx.x >> 7;
    int y = blockIdx.x & 127;
    __shared__ uint32_t tile[64][65];   // [c][x/2] packed fp16 pair; 65: 2-way-free

    const float* src = x + ((size_t)b * CIN) * (Hh * Wh) + (size_t)y * Wh;
    int t    = threadIdx.x;
    int xp   = t & 63;     // x-pair
    int csub = t >> 6;     // 0..3
    #pragma unroll
    for (int cc = 0; cc < 64; cc += 4) {
        int c = cc + csub;
        float2 v = *(const float2*)(src + (size_t)c * (Hh * Wh) + xp * 2);
        uint32_t h0 = (uint32_t)__builtin_bit_cast(uint16_t, (h16)v.x);
        uint32_t h1 = (uint32_t)__builtin_bit_cast(uint16_t, (h16)v.y);
        tile[c][xp] = h0 | (h1 << 16);
    }
    __syncthreads();

    uint32_t* dst = (uint32_t*)(g_xT + (((size_t)b * Hh + y) * Wh) * CIN);
    int d  = t & 31;
    int xo = t >> 5;
    #pragma unroll
    for (int it = 0; it < 16; ++it) {
        int xg = it * 8 + xo;
        uint32_t lo = tile[2 * d][xg >> 1];
        uint32_t hi = tile[2 * d + 1][xg >> 1];
        int sh = (xg & 1) * 16;
        uint32_t l0 = (lo >> sh) & 0xffffu;
        uint32_t h1 = (hi >> sh) & 0xffffu;
        dst[xg * 32 + d] = l0 | (h1 << 16);
    }
}

// ---------------------------------------------------------------------------
// dcn_main: 2048 blocks x 4 waves; wave = 16 pixels x all 64 COUT.
// Phase-split: all 27 offset/mask loads upfront; taps in groups of 3
// (24 gathers in flight before any MFMA consumes); fp16 pk-fma blend.
// b = blk&7: XCD-affine so each XCD L2 caches exactly one batch's xT (2MiB).
// ---------------------------------------------------------------------------
__global__ __launch_bounds__(256) void dcn_main(
        const float* __restrict__ offset, const float* __restrict__ mask,
        const float* __restrict__ bias, float* __restrict__ out) {
    int blk   = blockIdx.x;
    int b     = blk & 7;
    int strip = blk >> 3;
    int lane  = threadIdx.x & 63;
    int wave  = threadIdx.x >> 6;
    int n15   = lane & 15;
    int q     = lane >> 4;
    int p     = strip * 64 + wave * 16 + n15;
    int i     = p >> 7, j = p & 127;

    const float* offB = offset + (size_t)b * (2 * Tt * HW);
    const float* mskB = mask   + (size_t)b * (Tt * HW);
    const h16*   xb   = g_xT   + (size_t)b * (Hh * Wh * CIN);

    float dyv[Tt], dxv[Tt], mmv[Tt];
    #pragma unroll
    for (int t = 0; t < Tt; ++t) {
        dyv[t] = offB[(2 * t) * HW + p];
        dxv[t] = offB[(2 * t + 1) * HW + p];
        mmv[t] = mskB[t * HW + p];
    }

    f4 acc[4] = {{0.f,0.f,0.f,0.f},{0.f,0.f,0.f,0.f},
                 {0.f,0.f,0.f,0.f},{0.f,0.f,0.f,0.f}};

    #pragma unroll
    for (int tg = 0; tg < 3; ++tg) {
        h8 bfr[6];
        #pragma unroll
        for (int tl = 0; tl < 3; ++tl) {
            const int t  = tg * 3 + tl;
            const int ky = t / 3, kx = t % 3;
            float py = dyv[t] + (float)(i + ky - 1);
            float px = dxv[t] + (float)(j + kx - 1);
            float fy = floorf(py), fx = floorf(px);
            int   y0 = (int)fy,    x0 = (int)fx;
            float ly = py - fy,    lx = px - fx;
            float hy = 1.f - ly,   hx = 1.f - lx;

            bool vy0 = (y0 >= 0) && (y0 < Hh);
            bool vy1 = (y0 >= -1) && (y0 < Hh - 1);
            bool vx0 = (x0 >= 0) && (x0 < Wh);
            bool vx1 = (x0 >= -1) && (x0 < Wh - 1);
            float m = mmv[t];
            float w00 = (vy0 && vx0) ? hy * hx * m : 0.f;
            float w01 = (vy0 && vx1) ? hy * lx * m : 0.f;
            float w10 = (vy1 && vx0) ? ly * hx * m : 0.f;
            float w11 = (vy1 && vx1) ? ly * lx * m : 0.f;

            int y0c = min(max(y0, 0), Hh - 1), y1c = min(max(y0 + 1, 0), Hh - 1);
            int x0c = min(max(x0, 0), Wh - 1), x1c = min(max(x0 + 1, 0), Wh - 1);

            const h16* r0  = xb + (size_t)(y0c * Wh) * CIN;
            const h16* r1  = xb + (size_t)(y1c * Wh) * CIN;
            const h16* p00 = r0 + x0c * CIN;
            const h16* p01 = r0 + x1c * CIN;
            const h16* p10 = r1 + x0c * CIN;
            const h16* p11 = r1 + x1c * CIN;

            h2 W00 = {(h16)w00, (h16)w00};
            h2 W01 = {(h16)w01, (h16)w01};
            h2 W10 = {(h16)w10, (h16)w10};
            h2 W11 = {(h16)w11, (h16)w11};

            union U4 { uint4 v; h2 h[4]; };
            #pragma unroll
            for (int ks = 0; ks < 2; ++ks) {
                int c = q * 8 + ks * 32;
                U4 u00, u01, u10, u11;
                u00.v = *(const uint4*)(p00 + c);
                u01.v = *(const uint4*)(p01 + c);
                u10.v = *(const uint4*)(p10 + c);
                u11.v = *(const uint4*)(p11 + c);
                union { h2 r[4]; h8 v; } pk;
                #pragma unroll
                for (int e = 0; e < 4; ++e) {
                    h2 r = u00.h[e] * W00;
                    r = u01.h[e] * W01 + r;
                    r = u10.h[e] * W10 + r;
                    r = u11.h[e] * W11 + r;
                    pk.r[e] = r;
                }
                bfr[tl * 2 + ks] = pk.v;
            }
        }

        #pragma unroll
        for (int tl = 0; tl < 3; ++tl) {
            const h16* wt = g_wh + (tg * 3 + tl) * 4096;
            #pragma unroll
            for (int ks = 0; ks < 2; ++ks) {
                #pragma unroll
                for (int mt = 0; mt < 4; ++mt) {
                    h8 a = *(const h8*)(wt + ks * 2048 + mt * 512 + lane * 8);
                    acc[mt] = __builtin_amdgcn_mfma_f32_16x16x32_f16(
                        a, bfr[tl * 2 + ks], acc[mt], 0, 0, 0);
                }
            }
        }
    }

    #pragma unroll
    for (int mt = 0; mt < 4; ++mt) {
        #pragma unroll
        for (int r = 0; r < 4; ++r) {
            int o = mt * 16 + q * 4 + r;
            out[(size_t)(b * COUT + o) * HW + p] = acc[mt][r] + bias[o];
        }
    }
}

extern "C" void kernel_launch(void* const* d_in, const int* in_sizes, int n_in,
                              void* d_out, int out_size, void* d_ws, size_t ws_size,
                              hipStream_t stream) {
    const float* x      = (const float*)d_in[0];
    const float* offset = (const float*)d_in[1];
    const float* mask   = (const float*)d_in[2];
    const float* weight = (const float*)d_in[3];
    const float* bias   = (const float*)d_in[4];
    (void)d_ws; (void)ws_size;

    prep<<<Bn * Hh + 144, 256, 0, stream>>>(x, weight);
    dcn_main<<<Bn * 256, 256, 0, stream>>>(offset, mask, bias, (float*)d_out);
}

// Round 4
// 127.952 us; speedup vs baseline: 1.4293x; 1.3984x over previous
//
#include <hip/hip_runtime.h>
#include <stdint.h>

#define Bn   8
#define CIN  64
#define Hh   128
#define Wh   128
#define COUT 64
#define Tt   9
#define HO   128
#define WO   128
#define HW   (HO * WO)

// LDS-staged region per block: 8x8 pixel tile + halo 6 => 20x20 pixels,
// 64 ch fp16 = 128 B per pixel record, 400 records = 50 KiB (3 blocks/CU).
#define RW   20
#define RREC (RW * RW)
#define HALO 6

typedef _Float16 h16;
typedef __attribute__((ext_vector_type(2))) _Float16 h2;
typedef __attribute__((ext_vector_type(8))) _Float16 h8;
typedef __attribute__((ext_vector_type(4))) float   f4;

// Module-scope scratch (NOT d_ws: R1 overflowed ws_size and corrupted the
// harness's pristine inputs). 16 MiB fp16 NHWC x + 72 KiB fp16 weights.
__device__ h16 g_xT[(size_t)Bn * Hh * Wh * CIN];
__device__ h16 g_wh[Tt * COUT * CIN];

// ---------------------------------------------------------------------------
// prep: blocks [0,1024) transpose x NCHW fp32 -> g_xT NHWC fp16 (block per
// (b,y)); blocks [1024,1168) repack weight -> fp16 MFMA A-fragment order.
// ---------------------------------------------------------------------------
__global__ __launch_bounds__(256) void prep(const float* __restrict__ x,
                                            const float* __restrict__ w) {
    if (blockIdx.x >= Bn * Hh) {
        int tid = (blockIdx.x - Bn * Hh) * 256 + threadIdx.x;   // 36864
        int t   = tid >> 12;
        int rem = tid & 4095;
        int o   = rem >> 6;
        int c   = rem & 63;
        float v = w[(size_t)(o * 64 + c) * 9 + t];
        int ks = c >> 5, q = (c >> 3) & 3, j = c & 7;
        int mt = o >> 4, o15 = o & 15;
        g_wh[t * 4096 + ks * 2048 + mt * 512 + q * 128 + o15 * 8 + j] = (h16)v;
        return;
    }
    int b = blockIdx.x >> 7;
    int y = blockIdx.x & 127;
    __shared__ uint32_t tile[64][65];   // [c][x/2] packed fp16 pair

    const float* src = x + ((size_t)b * CIN) * (Hh * Wh) + (size_t)y * Wh;
    int t    = threadIdx.x;
    int xp   = t & 63;     // x-pair
    int csub = t >> 6;     // 0..3
    #pragma unroll
    for (int cc = 0; cc < 64; cc += 4) {
        int c = cc + csub;
        float2 v = *(const float2*)(src + (size_t)c * (Hh * Wh) + xp * 2);
        uint32_t h0 = (uint32_t)__builtin_bit_cast(uint16_t, (h16)v.x);
        uint32_t h1 = (uint32_t)__builtin_bit_cast(uint16_t, (h16)v.y);
        tile[c][xp] = h0 | (h1 << 16);
    }
    __syncthreads();

    uint32_t* dst = (uint32_t*)(g_xT + (((size_t)b * Hh + y) * Wh) * CIN);
    int d  = t & 31;
    int xo = t >> 5;
    #pragma unroll
    for (int it = 0; it < 16; ++it) {
        int xg = it * 8 + xo;
        uint32_t lo = tile[2 * d][xg >> 1];
        uint32_t hi = tile[2 * d + 1][xg >> 1];
        int sh = (xg & 1) * 16;
        uint32_t l0 = (lo >> sh) & 0xffffu;
        uint32_t h1 = (hi >> sh) & 0xffffu;
        dst[xg * 32 + d] = l0 | (h1 << 16);
    }
}

// ---------------------------------------------------------------------------
// dcn_main: 2048 blocks x 4 waves. Block tile = 8x8 pixels; wave w owns rows
// {2w,2w+1} x 8 cols (16 px) x all 64 COUT. x region staged in LDS with
// quad-XOR swizzle; bilinear corners read via ds_read_b128 (off the L1/TA
// path, which R3 counters showed was the address-divergence bottleneck).
// Out-of-tile samples (|offset| beyond halo, ~1e-4 of lanes) take a global
// fallback. b = blk&7: XCD-affine L2 (2 MiB xT slice per XCD).
// ---------------------------------------------------------------------------
__global__ __launch_bounds__(256) void dcn_main(
        const float* __restrict__ offset, const float* __restrict__ mask,
        const float* __restrict__ bias, float* __restrict__ out) {
    __shared__ __align__(16) uint8_t sreg[RREC * 128];   // 50 KiB

    int blk  = blockIdx.x;
    int b    = blk & 7;
    int s    = blk >> 3;            // tile id within batch, 256 tiles
    int ty   = s >> 4, tx = s & 15;
    int i0   = ty * 8, j0 = tx * 8;
    int lane = threadIdx.x & 63;
    int wave = threadIdx.x >> 6;
    int n15  = lane & 15;
    int q    = lane >> 4;

    const h16* xb = g_xT + (size_t)b * (Hh * Wh * CIN);

    // ---- stage region: 400 records x 8 quads = 3200 uint4 ----
    {
        const int base_y = i0 - HALO, base_x = j0 - HALO;
        #pragma unroll
        for (int it = 0; it < 13; ++it) {
            int idx  = it * 256 + threadIdx.x;
            int rec  = idx >> 3;
            int quad = idx & 7;
            if (rec < RREC) {
                int ry = rec / RW, rx = rec - ry * RW;
                int gy = min(max(base_y + ry, 0), Hh - 1);
                int gx = min(max(base_x + rx, 0), Wh - 1);
                uint4 v = *(const uint4*)(xb + ((gy << 7) + gx) * 64 + quad * 8);
                *(uint4*)(sreg + rec * 128 + ((quad ^ (rec & 7)) << 4)) = v;
            }
        }
    }
    __syncthreads();

    int i = i0 + (wave << 1) + (n15 >> 3);
    int j = j0 + (n15 & 7);
    int p = (i << 7) + j;

    const float* offB = offset + (size_t)b * (2 * Tt * HW);
    const float* mskB = mask   + (size_t)b * (Tt * HW);

    float dyv[Tt], dxv[Tt], mmv[Tt];
    #pragma unroll
    for (int t = 0; t < Tt; ++t) {
        dyv[t] = offB[(2 * t) * HW + p];
        dxv[t] = offB[(2 * t + 1) * HW + p];
        mmv[t] = mskB[t * HW + p];
    }

    f4 acc[4] = {{0.f,0.f,0.f,0.f},{0.f,0.f,0.f,0.f},
                 {0.f,0.f,0.f,0.f},{0.f,0.f,0.f,0.f}};

    #pragma unroll
    for (int t = 0; t < Tt; ++t) {
        const int ky = t / 3, kx = t % 3;
        float py = dyv[t] + (float)(i + ky - 1);
        float px = dxv[t] + (float)(j + kx - 1);
        float fy = floorf(py), fx = floorf(px);
        int   y0 = (int)fy,    x0 = (int)fx;
        float ly = py - fy,    lx = px - fx;
        float hy = 1.f - ly,   hx = 1.f - lx;

        bool vy0 = (y0 >= 0) && (y0 < Hh);
        bool vy1 = (y0 >= -1) && (y0 < Hh - 1);
        bool vx0 = (x0 >= 0) && (x0 < Wh);
        bool vx1 = (x0 >= -1) && (x0 < Wh - 1);
        float m = mmv[t];
        float w00 = (vy0 && vx0) ? hy * hx * m : 0.f;
        float w01 = (vy0 && vx1) ? hy * lx * m : 0.f;
        float w10 = (vy1 && vx0) ? ly * hx * m : 0.f;
        float w11 = (vy1 && vx1) ? ly * lx * m : 0.f;

        // region-local coords (halo 6, region 20x20; corner+1 needs <=19)
        int ry = y0 - i0 + HALO;
        int rx = x0 - j0 + HALO;
        bool intile = (ry >= 0) & (ry <= RW - 2) & (rx >= 0) & (rx <= RW - 2);
        int ryc = min(max(ry, 0), RW - 2), rxc = min(max(rx, 0), RW - 2);
        int pl00 = ryc * RW + rxc;
        int pl01 = pl00 + 1, pl10 = pl00 + RW, pl11 = pl00 + RW + 1;

        union U4 { uint4 v; h2 h[4]; };
        U4 c00[2], c01[2], c10[2], c11[2];
        #pragma unroll
        for (int ks = 0; ks < 2; ++ks) {
            int qd = q + ks * 4;   // logical quad (16B) within 128B record
            c00[ks].v = *(const uint4*)(sreg + pl00 * 128 + ((qd ^ (pl00 & 7)) << 4));
            c01[ks].v = *(const uint4*)(sreg + pl01 * 128 + ((qd ^ (pl01 & 7)) << 4));
            c10[ks].v = *(const uint4*)(sreg + pl10 * 128 + ((qd ^ (pl10 & 7)) << 4));
            c11[ks].v = *(const uint4*)(sreg + pl11 * 128 + ((qd ^ (pl11 & 7)) << 4));
        }
        if (__any(!intile)) {   // rare global fallback (offset beyond halo)
            if (!intile) {
                int y0c = min(max(y0, 0), Hh - 1), y1c = min(max(y0 + 1, 0), Hh - 1);
                int x0c = min(max(x0, 0), Wh - 1), x1c = min(max(x0 + 1, 0), Wh - 1);
                const h16* r0 = xb + (size_t)(y0c * Wh) * CIN;
                const h16* r1 = xb + (size_t)(y1c * Wh) * CIN;
                #pragma unroll
                for (int ks = 0; ks < 2; ++ks) {
                    int c = q * 8 + ks * 32;
                    c00[ks].v = *(const uint4*)(r0 + x0c * CIN + c);
                    c01[ks].v = *(const uint4*)(r0 + x1c * CIN + c);
                    c10[ks].v = *(const uint4*)(r1 + x0c * CIN + c);
                    c11[ks].v = *(const uint4*)(r1 + x1c * CIN + c);
                }
            }
        }

        h2 W00 = {(h16)w00, (h16)w00};
        h2 W01 = {(h16)w01, (h16)w01};
        h2 W10 = {(h16)w10, (h16)w10};
        h2 W11 = {(h16)w11, (h16)w11};

        h8 bfrag[2];
        #pragma unroll
        for (int ks = 0; ks < 2; ++ks) {
            union { h2 r[4]; h8 v; } pk;
            #pragma unroll
            for (int e = 0; e < 4; ++e) {
                h2 r = c00[ks].h[e] * W00;
                r = c01[ks].h[e] * W01 + r;
                r = c10[ks].h[e] * W10 + r;
                r = c11[ks].h[e] * W11 + r;
                pk.r[e] = r;
            }
            bfrag[ks] = pk.v;
        }

        const h16* wt = g_wh + t * 4096;
        #pragma unroll
        for (int ks = 0; ks < 2; ++ks) {
            #pragma unroll
            for (int mt = 0; mt < 4; ++mt) {
                h8 a = *(const h8*)(wt + ks * 2048 + mt * 512 + lane * 8);
                acc[mt] = __builtin_amdgcn_mfma_f32_16x16x32_f16(
                    a, bfrag[ks], acc[mt], 0, 0, 0);
            }
        }
    }

    #pragma unroll
    for (int mt = 0; mt < 4; ++mt) {
        #pragma unroll
        for (int r = 0; r < 4; ++r) {
            int o = mt * 16 + q * 4 + r;
            out[(size_t)(b * COUT + o) * HW + p] = acc[mt][r] + bias[o];
        }
    }
}

extern "C" void kernel_launch(void* const* d_in, const int* in_sizes, int n_in,
                              void* d_out, int out_size, void* d_ws, size_t ws_size,
                              hipStream_t stream) {
    const float* x      = (const float*)d_in[0];
    const float* offset = (const float*)d_in[1];
    const float* mask   = (const float*)d_in[2];
    const float* weight = (const float*)d_in[3];
    const float* bias   = (const float*)d_in[4];
    (void)d_ws; (void)ws_size;

    prep<<<Bn * Hh + 144, 256, 0, stream>>>(x, weight);
    dcn_main<<<Bn * 256, 256, 0, stream>>>(offset, mask, bias, (float*)d_out);
}